// Round 7
// baseline (523.323 us; speedup 1.0000x reference)
//
#include <hip/hip_runtime.h>
#include <hip/hip_fp16.h>

#define N_DST 100000
#define DIN 128
#define HDIM 64
#define RREL 3
#define NE 1000000

#define NBKT_REL 196              // ceil(100000/512) buckets per relation
#define NBKT (RREL * NBKT_REL)    // 588 total buckets
#define NSEG (RREL * N_DST)       // 300000 segments
#define EDGE_CHUNK 16384
#define NBLK_BIN ((RREL * NE + EDGE_CHUNK - 1) / EDGE_CHUNK)  // 184

typedef _Float16 f16x8 __attribute__((ext_vector_type(8)));
typedef float f32x4 __attribute__((ext_vector_type(4)));

// NOTE on the pi-permuted h/z dim layout used below:
//   storage slot s = (d & 15) * 4 + (d >> 4)   (d = natural h-dim, 0..63)
// k_gemm stores h16 rows pi-permuted (lets each lane write its 4 C-frag values
// as ONE 8B store -> fully coalesced). k_aggregate is dim-oblivious (z inherits
// pi). k_semantic permutes W1 rows at staging to match. k_final un-permutes
// via an LDS tile. el/er logits are computed from acc in natural order (pi-free).

// ---------------- W prep: Wt [mat][k=128][n=64] f32 -> W16 fp16, transposed to
// [mat][col][k] and PRE-SWIZZLED (byte ^= (col&7)<<4) so k_gemm stages it to LDS
// with a LINEAR copy and reads fragments conflict-free. 64 KB once.
__global__ __launch_bounds__(256) void k_wprep(const float* __restrict__ Wt,
                                               __half* __restrict__ W16) {
  int g = blockIdx.x * 256 + threadIdx.x;  // 0..4095: [mat][kb][col], col fastest
  int col = g & 63;
  int kb = (g >> 6) & 15;   // 16B (8 fp16) granule along k
  int mat = g >> 10;
  const float* wp = Wt + ((size_t)mat * DIN + kb * 8) * HDIM + col;
  f16x8 hv;
#pragma unroll
  for (int j = 0; j < 8; j++) hv[j] = (_Float16)wp[(size_t)j * HDIM];
  *(f16x8*)((unsigned char*)W16 + mat * 16384 + col * 256 + ((kb * 16) ^ ((col & 7) << 4))) = hv;
}

// ---------------- GEMM via MFMA: persistent pipelined version ----------------
// Grid 768 = 4 mats x 192 block-slots (3 blocks/CU, all resident). Each block
// stages W once, then loops over ~4 row-tiles (stride 192) with a 2-stage
// register double-buffer: the next half-tile's 8 dwordx4 A-loads are in flight
// under the current half-tile's cvt+MFMA and the tile epilogue. No barrier in
// the loop. h16 stored pi-packed: one 8B store per (rt,j) per lane.
__global__ __launch_bounds__(256) void k_gemm(
    const float* __restrict__ dst_feat, const float* __restrict__ neigh,
    const __half* __restrict__ W16, const float* __restrict__ bt,
    const float* __restrict__ attn_l, const float* __restrict__ attn_r,
    __half* __restrict__ h16, float* __restrict__ el, float* __restrict__ er) {
  const int RB = (N_DST + 127) / 128;  // 782 tiles per matrix
  int mat = blockIdx.x & 3;
  int bslot = blockIdx.x >> 2;  // 0..191
  const float* A = (mat == 0) ? dst_feat : (neigh + (size_t)(mat - 1) * N_DST * DIN);
  const float* b = bt + mat * HDIM;

  __shared__ __align__(16) unsigned char ldsW[16384];  // 64 cols x 128 k fp16 (swz)
  int tid = threadIdx.x;
  {
    const float4* wsrc = (const float4*)((const unsigned char*)W16 + (size_t)mat * 16384);
#pragma unroll
    for (int i = 0; i < 4; i++)
      *(float4*)(ldsW + (tid + 256 * i) * 16) = wsrc[tid + 256 * i];
  }
  int w = tid >> 6;
  int l = tid & 63;
  int li = l & 15;   // fragment row/col within tile
  int hi = l >> 4;   // k-quarter within fragment

  // hoisted per-lane constants
  float bv[4], av0[4], av1[4], av2[4];
#pragma unroll
  for (int ct = 0; ct < 4; ct++) bv[ct] = b[ct * 16 + li];
  if (mat == 0) {
#pragma unroll
    for (int ct = 0; ct < 4; ct++) {
      av0[ct] = attn_r[0 * HDIM + ct * 16 + li];
      av1[ct] = attn_r[1 * HDIM + ct * 16 + li];
      av2[ct] = attn_r[2 * HDIM + ct * 16 + li];
    }
  } else {
#pragma unroll
    for (int ct = 0; ct < 4; ct++) av0[ct] = attn_l[(mat - 1) * HDIM + ct * 16 + li];
  }

  auto cvt8 = [](const float4& v0, const float4& v1) {
    f16x8 h;
    h[0] = (_Float16)v0.x; h[1] = (_Float16)v0.y;
    h[2] = (_Float16)v0.z; h[3] = (_Float16)v0.w;
    h[4] = (_Float16)v1.x; h[5] = (_Float16)v1.y;
    h[6] = (_Float16)v1.z; h[7] = (_Float16)v1.w;
    return h;
  };

#define APTR(T, OFS) (A + (size_t)min((T) * 128 + w * 32 + li + (OFS), N_DST - 1) * DIN + hi * 8)

#define LOADH(P, PA, PB, H)                       \
  do {                                            \
    P[0] = *(const float4*)((PA) + (H) * 64);     \
    P[1] = *(const float4*)((PA) + (H) * 64 + 4); \
    P[2] = *(const float4*)((PB) + (H) * 64);     \
    P[3] = *(const float4*)((PB) + (H) * 64 + 4); \
    P[4] = *(const float4*)((PA) + (H) * 64 + 32);\
    P[5] = *(const float4*)((PA) + (H) * 64 + 36);\
    P[6] = *(const float4*)((PB) + (H) * 64 + 32);\
    P[7] = *(const float4*)((PB) + (H) * 64 + 36);\
  } while (0)

#define COMPH(P, H)                                                                        \
  do {                                                                                     \
    f16x8 fa0 = cvt8(P[0], P[1]);                                                          \
    f16x8 fb0 = cvt8(P[2], P[3]);                                                          \
    int kb0 = (2 * (H)) * 64 + hi * 16;                                                    \
    _Pragma("unroll") for (int ct = 0; ct < 4; ct++) {                                     \
      int col = ct * 16 + li;                                                              \
      f16x8 bf = *(f16x8*)(ldsW + col * 256 + (kb0 ^ ((col & 7) << 4)));                   \
      acc[0][ct] = __builtin_amdgcn_mfma_f32_16x16x32_f16(fa0, bf, acc[0][ct], 0, 0, 0);   \
      acc[1][ct] = __builtin_amdgcn_mfma_f32_16x16x32_f16(fb0, bf, acc[1][ct], 0, 0, 0);   \
    }                                                                                      \
    f16x8 fa1 = cvt8(P[4], P[5]);                                                          \
    f16x8 fb1 = cvt8(P[6], P[7]);                                                          \
    int kb1 = (2 * (H) + 1) * 64 + hi * 16;                                                \
    _Pragma("unroll") for (int ct = 0; ct < 4; ct++) {                                     \
      int col = ct * 16 + li;                                                              \
      f16x8 bf = *(f16x8*)(ldsW + col * 256 + (kb1 ^ ((col & 7) << 4)));                   \
      acc[0][ct] = __builtin_amdgcn_mfma_f32_16x16x32_f16(fa1, bf, acc[0][ct], 0, 0, 0);   \
      acc[1][ct] = __builtin_amdgcn_mfma_f32_16x16x32_f16(fb1, bf, acc[1][ct], 0, 0, 0);   \
    }                                                                                      \
  } while (0)

#define RELRED(AV, DST)                                                                \
  do {                                                                                 \
    _Pragma("unroll") for (int rt = 0; rt < 2; rt++) {                                 \
      float p[4];                                                                      \
      _Pragma("unroll") for (int j = 0; j < 4; j++)                                    \
          p[j] = acc[rt][0][j] * AV[0] + acc[rt][1][j] * AV[1] +                        \
                 acc[rt][2][j] * AV[2] + acc[rt][3][j] * AV[3];                         \
      _Pragma("unroll") for (int o = 1; o < 16; o <<= 1)                               \
        _Pragma("unroll") for (int j = 0; j < 4; j++) p[j] += __shfl_xor(p[j], o);     \
      if (li == 0) {                                                                   \
        _Pragma("unroll") for (int j = 0; j < 4; j++) {                                \
          int gr = trow + rt * 16 + hi * 4 + j;                                        \
          if (gr < N_DST) (DST)[gr] = p[j];                                            \
        }                                                                              \
      }                                                                                \
    }                                                                                  \
  } while (0)

  float4 P0[8], P1[8];
  int t = bslot;
  const float* pa = APTR(t, 0);
  const float* pb = APTR(t, 16);
  LOADH(P0, pa, pb, 0);
  __syncthreads();  // ldsW ready (drains initial loads too; loop has no barrier)

  for (;;) {
    LOADH(P1, pa, pb, 1);
    f32x4 acc[2][4] = {};
    COMPH(P0, 0);
    int tn = t + 192;
    bool more = tn < RB;
    const float* pan = pa;
    const float* pbn = pb;
    if (more) {
      pan = APTR(tn, 0);
      pbn = APTR(tn, 16);
      LOADH(P0, pan, pbn, 0);  // next tile's loads fly under COMPH(P1)+epilogue
    }
    COMPH(P1, 1);

    // ---- tile epilogue: bias, logits, pi-packed h16 store ----
    int trow = t * 128 + w * 32;
#pragma unroll
    for (int rt = 0; rt < 2; rt++)
#pragma unroll
      for (int ct = 0; ct < 4; ct++)
#pragma unroll
        for (int j = 0; j < 4; j++) acc[rt][ct][j] += bv[ct];

    if (mat == 0) {
      RELRED(av0, er + 0 * N_DST);
      RELRED(av1, er + 1 * N_DST);
      RELRED(av2, er + 2 * N_DST);
    } else {
      RELRED(av0, el + (size_t)(mat - 1) * N_DST);
      __half* hb = h16 + (size_t)(mat - 1) * N_DST * HDIM;
#pragma unroll
      for (int rt = 0; rt < 2; rt++)
#pragma unroll
        for (int j = 0; j < 4; j++) {
          int gr = trow + rt * 16 + hi * 4 + j;
          if (gr < N_DST) {
            union { __half2 h2[2]; float2 f2; } u;
            u.h2[0] = __floats2half2_rn(acc[rt][0][j], acc[rt][1][j]);
            u.h2[1] = __floats2half2_rn(acc[rt][2][j], acc[rt][3][j]);
            // slot s = li*4 + ct  (pi layout) -> one 8B store, wave covers 4x128B rows
            *(float2*)(hb + (size_t)gr * HDIM + li * 4) = u.f2;
          }
        }
    }
    if (!more) break;
    t = tn; pa = pan; pb = pbn;
  }
#undef APTR
#undef LOADH
#undef COMPH
#undef RELRED
}

// ---------------- CSR build: counting-sort partition, zero global atomics ----------------

__global__ __launch_bounds__(256) void k_hist(const int* __restrict__ dst_idx,
                                              int* __restrict__ hist) {
  __shared__ int h[NBKT];
  int tid = threadIdx.x;
  int blk = blockIdx.x;
  for (int i = tid; i < NBKT; i += 256) h[i] = 0;
  __syncthreads();
  int e0 = blk * EDGE_CHUNK;
  int e1 = min(e0 + EDGE_CHUNK, RREL * NE);
  for (int idx = e0 + tid; idx < e1; idx += 256) {
    int r = idx / NE;
    int d = dst_idx[idx];
    atomicAdd(&h[r * NBKT_REL + (d >> 9)], 1);
  }
  __syncthreads();
  for (int i = tid; i < NBKT; i += 256)
    hist[(size_t)i * NBLK_BIN + blk] = h[i];
}

__global__ __launch_bounds__(256) void k_colscan(int* __restrict__ hist,
                                                 int* __restrict__ bcounts) {
  __shared__ int sm[256];
  int b = blockIdx.x;
  int tid = threadIdx.x;
  int v = (tid < NBLK_BIN) ? hist[(size_t)b * NBLK_BIN + tid] : 0;
  sm[tid] = v;
  __syncthreads();
  for (int off = 1; off < 256; off <<= 1) {
    int t = (tid >= off) ? sm[tid - off] : 0;
    __syncthreads();
    sm[tid] += t;
    __syncthreads();
  }
  if (tid < NBLK_BIN) hist[(size_t)b * NBLK_BIN + tid] = sm[tid] - v;  // exclusive
  if (tid == 255) bcounts[b] = sm[255];
}

__global__ __launch_bounds__(256) void k_bscan(const int* __restrict__ bcounts,
                                               int* __restrict__ bucket_base,
                                               int* __restrict__ offsets) {
  __shared__ int sm[256];
  int tid = threadIdx.x;
  int base = tid * 3;
  int c[3];
#pragma unroll
  for (int k = 0; k < 3; k++) c[k] = (base + k < NBKT) ? bcounts[base + k] : 0;
  int tsum = c[0] + c[1] + c[2];
  sm[tid] = tsum;
  __syncthreads();
  for (int off = 1; off < 256; off <<= 1) {
    int v = (tid >= off) ? sm[tid - off] : 0;
    __syncthreads();
    sm[tid] += v;
    __syncthreads();
  }
  int run = sm[tid] - tsum;
#pragma unroll
  for (int k = 0; k < 3; k++) {
    if (base + k < NBKT) bucket_base[base + k] = run;
    run += c[k];
  }
  if (tid == 255) bucket_base[NBKT] = sm[255];  // = RREL*NE
  if (tid == 0) offsets[NSEG] = RREL * NE;
}

__global__ __launch_bounds__(256) void k_place(const int* __restrict__ src_idx,
                                               const int* __restrict__ dst_idx,
                                               const int* __restrict__ hist,
                                               const int* __restrict__ bucket_base,
                                               unsigned* __restrict__ tmp) {
  __shared__ int cur[NBKT];
  int tid = threadIdx.x;
  int blk = blockIdx.x;
  for (int i = tid; i < NBKT; i += 256)
    cur[i] = bucket_base[i] + hist[(size_t)i * NBLK_BIN + blk];
  __syncthreads();
  int e0 = blk * EDGE_CHUNK;
  int e1 = min(e0 + EDGE_CHUNK, RREL * NE);
  for (int idx = e0 + tid; idx < e1; idx += 256) {
    int r = idx / NE;
    int d = dst_idx[idx];
    int s = src_idx[idx];
    int bucket = r * NBKT_REL + (d >> 9);
    int pos = atomicAdd(&cur[bucket], 1);
    tmp[pos] = ((unsigned)(d & 511) << 17) | (unsigned)s;
  }
}

__global__ __launch_bounds__(256) void k_bucket_csr(
    const int* __restrict__ bucket_base, const unsigned* __restrict__ tmp,
    int* __restrict__ src_sorted, int* __restrict__ offsets) {
  __shared__ int cnt[512];
  __shared__ int base_l[512];
  __shared__ int sm[256];
  int b = blockIdx.x;
  int r = b / NBKT_REL;
  int brel = b - r * NBKT_REL;
  int gbase = bucket_base[b];
  int gend = bucket_base[b + 1];
  int tid = threadIdx.x;
  cnt[tid] = 0;
  cnt[tid + 256] = 0;
  __syncthreads();
  for (int e = gbase + tid; e < gend; e += 256)
    atomicAdd(&cnt[tmp[e] >> 17], 1);
  __syncthreads();
  int c0 = cnt[2 * tid], c1 = cnt[2 * tid + 1];
  int tsum = c0 + c1;
  sm[tid] = tsum;
  __syncthreads();
  for (int off = 1; off < 256; off <<= 1) {
    int v = (tid >= off) ? sm[tid - off] : 0;
    __syncthreads();
    sm[tid] += v;
    __syncthreads();
  }
  int run = sm[tid] - tsum;
  base_l[2 * tid] = run;
  base_l[2 * tid + 1] = run + c0;
  __syncthreads();
  for (int s = tid; s < 512; s += 256) {
    int dst = (brel << 9) + s;
    if (dst < N_DST) offsets[r * N_DST + dst] = gbase + base_l[s];
    cnt[s] = 0;
  }
  __syncthreads();
  for (int e = gbase + tid; e < gend; e += 256) {
    unsigned w = tmp[e];
    int s = w >> 17;
    int pos = gbase + base_l[s] + atomicAdd(&cnt[s], 1);
    src_sorted[pos] = (int)(w & 0x1FFFFu);
  }
}

// ---------------- GAT aggregation: 8 lanes per (relation, dst-node) ----------------
// Dim-oblivious: works identically on the pi-permuted h16 rows; z inherits pi.
__global__ __launch_bounds__(256) void k_aggregate(
    const int* __restrict__ offsets, const int* __restrict__ src_sorted,
    const float* __restrict__ el, const float* __restrict__ er,
    const __half* __restrict__ h16, float* __restrict__ zbuf) {
  int gw = blockIdx.x * 32 + (threadIdx.x >> 3);
  int li = threadIdx.x & 7;  // lane-in-group: slots 8*li .. 8*li+7
  if (gw >= NSEG) return;
  int r = gw / N_DST;
  int start = offsets[gw], end = offsets[gw + 1];
  float erv = er[gw];
  const unsigned char* hs = (const unsigned char*)(h16 + (size_t)r * N_DST * HDIM);
  const float* elr = el + (size_t)r * N_DST;
  float acc[8] = {};
  float ssum = 0.f;
  int sNext = (start < end) ? src_sorted[start] : 0;  // 1-deep index prefetch
  for (int e = start; e < end; ++e) {
    int s = sNext;
    if (e + 1 < end) sNext = src_sorted[e + 1];
    float x = elr[s] + erv;                     // broadcast gather (L2-resident)
    float4 rv = *(const float4*)(hs + (unsigned)(s * 128 + li * 16));
    x = (x > 0.f) ? x : 0.01f * x;              // leaky_relu
    float a = __expf(x);
    ssum += a;
    const __half2* hp = (const __half2*)&rv;
#pragma unroll
    for (int q = 0; q < 4; q++) {
      float2 f = __half22float2(hp[q]);
      acc[2 * q] += a * f.x;
      acc[2 * q + 1] += a * f.y;
    }
  }
  float inv = (end > start) ? 1.f / ssum : 0.f;
  float zv[8];
#pragma unroll
  for (int q = 0; q < 8; q++) {
    float v = acc[q] * inv;
    zv[q] = (v > 0.f) ? v : (__expf(v) - 1.f);  // elu; empty segment -> elu(0)=0
  }
  float* zp = zbuf + (size_t)gw * HDIM + li * 8;
  *(float4*)zp = make_float4(zv[0], zv[1], zv[2], zv[3]);
  *(float4*)(zp + 4) = make_float4(zv[4], zv[5], zv[6], zv[7]);
}

// ---------------- semantic attention reduce (MFMA) ----------------
// z' (pi-permuted dims) @ W1' where W1' rows are pi-permuted at staging:
// source row for LDS k-index k is d(k) = (k&3)*16 + (k>>2).
__global__ __launch_bounds__(256) void k_semantic(
    const float* __restrict__ zbuf, const float* __restrict__ W1,
    const float* __restrict__ b1, const float* __restrict__ w2,
    float* __restrict__ w_acc) {
  __shared__ __align__(16) unsigned char lds[32 * 1024];
  unsigned char* ldsZ = lds;           // 128 rows x 64 k fp16 (stride 128B, swz)
  unsigned char* ldsW = lds + 16384;   // 128 cols x 64 k fp16 (stride 128B, swz)
  __shared__ float wsum[RREL];
  int tid = threadIdx.x;
  if (tid < RREL) wsum[tid] = 0.f;
  int row0 = blockIdx.x * 128;

  // ---- stage W1 with pi row-permutation: [k=64][n=128] f32 -> [col][k'] fp16 ----
  {
    int col = tid & 127;
    int kq = tid >> 7;  // 0..1 (k chunk of 32)
    float wr[32];
#pragma unroll
    for (int m = 0; m < 32; m++) {
      int k = kq * 32 + m;
      int srck = (k & 3) * 16 + (k >> 2);  // natural W1 row for permuted slot k
      wr[m] = W1[(size_t)srck * 128 + col];
    }
#pragma unroll
    for (int m8 = 0; m8 < 4; m8++) {
      f16x8 hv;
#pragma unroll
      for (int j = 0; j < 8; j++) hv[j] = (_Float16)wr[m8 * 8 + j];
      int byt = kq * 64 + m8 * 16;  // = k*2
      *(f16x8*)(ldsW + col * 128 + (byt ^ ((col & 7) << 4))) = hv;
    }
  }
  // ---- stage z: 128 rows x 64 f32 -> fp16 [row][k] swizzled (positional) ----
#pragma unroll
  for (int i = 0; i < 4; i++) {
    int s = tid + 256 * i;  // 0..1023
    int row = s >> 3;       // 0..127
    int kb = s & 7;         // 16B (8 fp16) chunk along k
    int gr = row0 + row;
    if (gr >= NSEG) gr = NSEG - 1;  // clamp (tail; guarded at atomicAdd)
    const float* zp = zbuf + (size_t)gr * HDIM + kb * 8;
    float4 v0 = *(const float4*)zp;
    float4 v1 = *(const float4*)(zp + 4);
    f16x8 hv;
    hv[0] = (_Float16)v0.x; hv[1] = (_Float16)v0.y;
    hv[2] = (_Float16)v0.z; hv[3] = (_Float16)v0.w;
    hv[4] = (_Float16)v1.x; hv[5] = (_Float16)v1.y;
    hv[6] = (_Float16)v1.z; hv[7] = (_Float16)v1.w;
    *(f16x8*)(ldsZ + row * 128 + ((kb * 16) ^ ((row & 7) << 4))) = hv;
  }
  __syncthreads();

  // ---- MFMA: wave w owns rows w*32..w*32+31 (2 M-tiles) x 128 cols (8 N-tiles) ----
  int w = tid >> 6;
  int l = tid & 63;
  int li = l & 15;  // col within tile
  int hi = l >> 4;  // k-quarter / row-quarter
  f32x4 acc[2][8] = {};
#pragma unroll
  for (int ks = 0; ks < 2; ks++) {
    int kbyte = ks * 64 + hi * 16;
    f16x8 af[2], bf[8];
#pragma unroll
    for (int rt = 0; rt < 2; rt++) {
      int row = w * 32 + rt * 16 + li;
      af[rt] = *(f16x8*)(ldsZ + row * 128 + (kbyte ^ ((row & 7) << 4)));
    }
#pragma unroll
    for (int ct = 0; ct < 8; ct++) {
      int col = ct * 16 + li;
      bf[ct] = *(f16x8*)(ldsW + col * 128 + (kbyte ^ ((col & 7) << 4)));
    }
#pragma unroll
    for (int rt = 0; rt < 2; rt++)
#pragma unroll
      for (int ct = 0; ct < 8; ct++)
        acc[rt][ct] = __builtin_amdgcn_mfma_f32_16x16x32_f16(af[rt], bf[ct], acc[rt][ct], 0, 0, 0);
  }

  // ---- epilogue: tanh(x+b1) . w2, reduce over cols ----
  float p[2][4] = {};
#pragma unroll
  for (int ct = 0; ct < 8; ct++) {
    float b1v = b1[ct * 16 + li];
    float w2v = w2[ct * 16 + li];
#pragma unroll
    for (int rt = 0; rt < 2; rt++)
#pragma unroll
      for (int j = 0; j < 4; j++) {
        float x = acc[rt][ct][j] + b1v;
        float ex = __expf(2.f * x);
        p[rt][j] += (1.f - 2.f / (ex + 1.f)) * w2v;  // tanh
      }
  }
#pragma unroll
  for (int o = 1; o < 16; o <<= 1)
#pragma unroll
    for (int rt = 0; rt < 2; rt++)
#pragma unroll
      for (int j = 0; j < 4; j++) p[rt][j] += __shfl_xor(p[rt][j], o);
  if (li == 0) {
#pragma unroll
    for (int rt = 0; rt < 2; rt++)
#pragma unroll
      for (int j = 0; j < 4; j++) {
        int row = row0 + w * 32 + rt * 16 + hi * 4 + j;
        if (row < NSEG) atomicAdd(&wsum[row / N_DST], p[rt][j]);
      }
  }
  __syncthreads();
  if (tid < RREL) atomicAdd(&w_acc[tid], wsum[tid]);
}

// ---------------- softmax over relations + weighted combine (+ pi un-permute) ----
// Block = 64 nodes. Phase 1: combine 3 relations reading z' coalesced into LDS.
// Phase 2: each thread writes 16 natural dims (64B) reading LDS at s(d)=(d&15)*4+(d>>4).
__global__ __launch_bounds__(256) void k_final(const float* __restrict__ zbuf,
                                               const float* __restrict__ w_acc,
                                               float* __restrict__ out) {
  __shared__ float c[64][68];  // +4 pad
  int tid = threadIdx.x;
  int n0 = blockIdx.x * 64;
  const float invN = 1.0f / N_DST;
  float w0 = w_acc[0] * invN, w1 = w_acc[1] * invN, w2v = w_acc[2] * invN;
  float m = fmaxf(w0, fmaxf(w1, w2v));
  float e0 = __expf(w0 - m), e1 = __expf(w1 - m), e2 = __expf(w2v - m);
  float inv = 1.f / (e0 + e1 + e2);
  e0 *= inv; e1 *= inv; e2 *= inv;
  const size_t stride = (size_t)N_DST * HDIM;
#pragma unroll
  for (int i = 0; i < 4; i++) {
    int idx = tid + 256 * i;  // 0..1023 float4-slots (64 nodes x 16)
    int nl = idx >> 4;
    int q = idx & 15;
    int n = n0 + nl;
    float4 rv = make_float4(0.f, 0.f, 0.f, 0.f);
    if (n < N_DST) {
      size_t o = (size_t)n * HDIM + q * 4;
      float4 z0 = *(const float4*)(zbuf + o);
      float4 z1 = *(const float4*)(zbuf + stride + o);
      float4 z2 = *(const float4*)(zbuf + 2 * stride + o);
      rv.x = e0 * z0.x + e1 * z1.x + e2 * z2.x;
      rv.y = e0 * z0.y + e1 * z1.y + e2 * z2.y;
      rv.z = e0 * z0.z + e1 * z1.z + e2 * z2.z;
      rv.w = e0 * z0.w + e1 * z1.w + e2 * z2.w;
    }
    *(float4*)(&c[nl][q * 4]) = rv;
  }
  __syncthreads();
  int nl = tid >> 2;
  int dq = tid & 3;  // owns natural dims dq*16 .. dq*16+15
  int n = n0 + nl;
  if (n < N_DST) {
    float o16[16];
#pragma unroll
    for (int i = 0; i < 16; i++) o16[i] = c[nl][i * 4 + dq];  // s(dq*16+i) = i*4+dq
    float4* op = (float4*)(out + (size_t)n * HDIM + dq * 16);
#pragma unroll
    for (int qq = 0; qq < 4; qq++)
      op[qq] = make_float4(o16[qq * 4], o16[qq * 4 + 1], o16[qq * 4 + 2], o16[qq * 4 + 3]);
  }
}

extern "C" void kernel_launch(void* const* d_in, const int* in_sizes, int n_in,
                              void* d_out, int out_size, void* d_ws, size_t ws_size,
                              hipStream_t stream) {
  const float* dst_feat = (const float*)d_in[0];
  const float* neigh = (const float*)d_in[1];
  const float* Wt = (const float*)d_in[2];
  const float* bt = (const float*)d_in[3];
  const float* attn_l = (const float*)d_in[4];
  const float* attn_r = (const float*)d_in[5];
  const float* W1 = (const float*)d_in[6];
  const float* b1 = (const float*)d_in[7];
  const float* w2 = (const float*)d_in[8];
  const int* src_idx = (const int*)d_in[9];
  const int* dst_idx = (const int*)d_in[10];
  float* out = (float*)d_out;

  char* p = (char*)d_ws;
  auto alloc = [&](size_t bytes) {
    char* q = p;
    p += (bytes + 255) & ~(size_t)255;
    return (void*)q;
  };
  __half* h16 = (__half*)alloc((size_t)RREL * N_DST * HDIM * 2);
  __half* W16 = (__half*)alloc((size_t)(RREL + 1) * HDIM * DIN * 2);  // 64 KB
  float* el = (float*)alloc((size_t)RREL * N_DST * 4);
  float* er = (float*)alloc((size_t)RREL * N_DST * 4);
  float* zbuf = (float*)alloc((size_t)RREL * N_DST * HDIM * 4);
  float* w_acc = (float*)alloc(64);
  int* offsets = (int*)alloc(((size_t)NSEG + 1) * 4);
  int* hist = (int*)alloc((size_t)NBKT * NBLK_BIN * 4);
  int* bcounts = (int*)alloc((size_t)NBKT * 4);
  int* bucket_base = (int*)alloc((size_t)(NBKT + 1) * 4);
  unsigned* tmp = (unsigned*)alloc((size_t)RREL * NE * 4);
  int* src_sorted = (int*)alloc((size_t)RREL * NE * 4);

  hipMemsetAsync(w_acc, 0, 64, stream);

  k_wprep<<<16, 256, 0, stream>>>(Wt, W16);
  k_gemm<<<768, 256, 0, stream>>>(dst_feat, neigh, W16, bt, attn_l, attn_r, h16, el, er);
  k_hist<<<NBLK_BIN, 256, 0, stream>>>(dst_idx, hist);
  k_colscan<<<NBKT, 256, 0, stream>>>(hist, bcounts);
  k_bscan<<<1, 256, 0, stream>>>(bcounts, bucket_base, offsets);
  k_place<<<NBLK_BIN, 256, 0, stream>>>(src_idx, dst_idx, hist, bucket_base, tmp);
  k_bucket_csr<<<NBKT, 256, 0, stream>>>(bucket_base, tmp, src_sorted, offsets);
  k_aggregate<<<(NSEG + 31) / 32, 256, 0, stream>>>(offsets, src_sorted, el, er, h16, zbuf);
  k_semantic<<<(NSEG + 127) / 128, 256, 0, stream>>>(zbuf, W1, b1, w2, w_acc);
  k_final<<<(N_DST + 63) / 64, 256, 0, stream>>>(zbuf, w_acc, out);
}